// Round 2
// baseline (667.584 us; speedup 1.0000x reference)
//
#include <hip/hip_runtime.h>
#include <math.h>

#define Bb 128
#define Tt 1024
#define Ll 96

typedef float v2f __attribute__((ext_vector_type(2)));
typedef float v4f __attribute__((ext_vector_type(4)));

// One block per batch, ONE wave (64 threads) per block — no __syncthreads in
// the scan loop, so global x-prefetch loads are never drained by barrier
// semantics (the R1 bottleneck). Lane k owns column c0=k and column
// c1=64+(k&31) (lanes 32..63 compute a masked duplicate of c1). E columns in
// VGPRs; p = exp(state - shift) in LDS, single-buffered (same-wave LDS
// ordering via lgkmcnt, no barrier needed).
__global__ __launch_bounds__(64, 1) void crf_fwd_kernel(
    const float* __restrict__ inputs,      // (B, T, L) fp32
    const int*   __restrict__ labels_idx,  // (B, T) int32
    const float* __restrict__ trans,       // (L, L) fp32
    float*       __restrict__ out)         // (B, 1) fp32
{
    const int b   = blockIdx.x;
    const int tid = threadIdx.x;          // 0..63
    const int c0  = tid;                  // columns 0..63
    const int c1  = 64 + (tid & 31);      // columns 64..95 (dup on lanes 32..63)
    const bool w1 = (tid < 32);

    __shared__ __align__(16) float p[Ll];

    const float* xbase = inputs + (size_t)b * Tt * Ll;

    // ---- E columns in registers: E0[l]=exp(trans[l][c0]), E1[l]=exp(trans[l][c1]) ----
    float E0[Ll], E1[Ll];
    #pragma unroll
    for (int l = 0; l < Ll; ++l) {
        E0[l] = __expf(trans[l * Ll + c0]);
        E1[l] = __expf(trans[l * Ll + c1]);
    }

    // ---- point_score + trans_score (off critical path, once) ----
    float score;
    {
        float psum = 0.f;
        const int* lbase = labels_idx + b * Tt;
        for (int t = tid; t < Tt; t += 64) {
            int i0 = lbase[t];
            psum += xbase[t * Ll + i0];
            if (t < Tt - 1) psum += trans[i0 * Ll + lbase[t + 1]];
        }
        #pragma unroll
        for (int off = 32; off; off >>= 1) psum += __shfl_xor(psum, off, 64);
        score = psum;   // full sum in every lane
    }

    // ---- init: P_0 = exp(state_0 - 0) ----
    p[c0] = __expf(xbase[c0]);
    if (w1) p[c1] = __expf(xbase[c1]);

    // ---- x prefetch pipeline, depth 4, both columns ----
    float x0a = xbase[1 * Ll + c0], x1a = xbase[1 * Ll + c1];
    float x0b = xbase[2 * Ll + c0], x1b = xbase[2 * Ll + c1];
    float x0c = xbase[3 * Ll + c0], x1c = xbase[3 * Ll + c1];
    float x0d = xbase[4 * Ll + c0], x1d = xbase[4 * Ll + c1];

    // c: constant s.t. true state_t = tval + c.  uP: shift used writing P_{t-1}.
    // uNext: shift for writing P_t (stale normalizer: tval_{t-1}[col 0]).
    float c = 0.f, uP = 0.f, uNext = 0.f;
    float t0 = 0.f, t1 = 0.f;

    for (int t = 1; t < Tt; ++t) {
        // prefetch x row t+4 (stays in flight — no barrier to drain it)
        float xn0 = 0.f, xn1 = 0.f;
        if (t + 4 < Tt) {
            xn0 = xbase[(t + 4) * Ll + c0];
            xn1 = xbase[(t + 4) * Ll + c1];
        }

        // ---- acc[c] = sum_l p[l] * E[l][c]  (broadcast b128 reads, pk-FMA) ----
        v2f a0 = {0.f, 0.f}, a1 = {0.f, 0.f};   // column c0, 2 chains
        v2f b0 = {0.f, 0.f}, b1 = {0.f, 0.f};   // column c1, 2 chains
        #pragma unroll
        for (int j = 0; j < Ll / 4; ++j) {
            v4f p4 = *reinterpret_cast<const v4f*>(&p[4 * j]);
            v2f plo = {p4.x, p4.y};
            v2f phi = {p4.z, p4.w};
            a0 += plo * (v2f){E0[4 * j],     E0[4 * j + 1]};
            a1 += phi * (v2f){E0[4 * j + 2], E0[4 * j + 3]};
            b0 += plo * (v2f){E1[4 * j],     E1[4 * j + 1]};
            b1 += phi * (v2f){E1[4 * j + 2], E1[4 * j + 3]};
        }
        v2f s0 = a0 + a1; float tot0 = s0.x + s0.y;
        v2f s1 = b0 + b1; float tot1 = s1.x + s1.y;

        c += uP;
        t0 = __logf(tot0) + x0a;          // state_t[c0] = t0 + c
        t1 = __logf(tot1) + x1a;          // state_t[c1] = t1 + c
        float un  = __shfl(t0, 0, 64);    // tval_t[col 0] — next step's shift
        float pn0 = __expf(t0 - uNext);
        float pn1 = __expf(t1 - uNext);
        p[c0] = pn0;
        if (w1) p[c1] = pn1;
        uP = uNext; uNext = un;

        x0a = x0b; x0b = x0c; x0c = x0d; x0d = xn0;
        x1a = x1b; x1b = x1c; x1c = x1d; x1d = xn1;
    }

    // ---- log_norm = logsumexp over 96 states (wave-local shfl reductions) ----
    float m0 = fmaxf(t0, w1 ? t1 : -INFINITY);
    #pragma unroll
    for (int off = 32; off; off >>= 1) m0 = fmaxf(m0, __shfl_xor(m0, off, 64));
    float e = __expf(t0 - m0) + (w1 ? __expf(t1 - m0) : 0.f);
    #pragma unroll
    for (int off = 32; off; off >>= 1) e += __shfl_xor(e, off, 64);

    if (tid == 0) {
        out[b] = m0 + __logf(e) + c - score;
    }
}

extern "C" void kernel_launch(void* const* d_in, const int* in_sizes, int n_in,
                              void* d_out, int out_size, void* d_ws, size_t ws_size,
                              hipStream_t stream) {
    const float* inputs     = (const float*)d_in[0];
    const int*   labels_idx = (const int*)d_in[1];
    const float* trans      = (const float*)d_in[2];
    float*       out        = (float*)d_out;

    crf_fwd_kernel<<<dim3(Bb), dim3(64), 0, stream>>>(inputs, labels_idx, trans, out);
}

// Round 3
// 614.836 us; speedup vs baseline: 1.0858x; 1.0858x over previous
//
#include <hip/hip_runtime.h>
#include <math.h>

#define Bb 128
#define Tt 1024
#define Ll 96

typedef float v2f __attribute__((ext_vector_type(2)));
typedef float v4f __attribute__((ext_vector_type(4)));

// One block per batch, ONE wave, no barriers. Lane pair (m, m+32) with j=m&31
// owns columns {j, 32+j, 64+j}; half h=m>>5 covers K-range [48h,48h+48).
// E entries are explicit scalar v2f variables (macro-expanded) so they CANNOT
// be demoted to scratch (the R1/R2 failure: VGPR_Count 68/124 < E size proved
// the E arrays lived in scratch memory). p = exp(state - stale-shift) in LDS.

#define REP48(M) M(0) M(1) M(2) M(3) M(4) M(5) M(6) M(7) M(8) M(9) M(10) M(11) \
  M(12) M(13) M(14) M(15) M(16) M(17) M(18) M(19) M(20) M(21) M(22) M(23) \
  M(24) M(25) M(26) M(27) M(28) M(29) M(30) M(31) M(32) M(33) M(34) M(35) \
  M(36) M(37) M(38) M(39) M(40) M(41) M(42) M(43) M(44) M(45) M(46) M(47)
#define REP24(M) M(0) M(1) M(2) M(3) M(4) M(5) M(6) M(7) M(8) M(9) M(10) M(11) \
  M(12) M(13) M(14) M(15) M(16) M(17) M(18) M(19) M(20) M(21) M(22) M(23)

__global__ __launch_bounds__(64, 1) void crf_fwd_kernel(
    const float* __restrict__ inputs,      // (B, T, L) fp32
    const int*   __restrict__ labels_idx,  // (B, T) int32
    const float* __restrict__ trans,       // (L, L) fp32
    float*       __restrict__ out)         // (B, 1) fp32
{
    const int b    = blockIdx.x;
    const int tid  = threadIdx.x;        // 0..63
    const int j    = tid & 31;
    const int half = tid >> 5;
    const int cA   = j;                  // columns owned by this lane pair
    const int cB   = 32 + j;
    const int cC   = 64 + j;
    const int lbase = 48 * half;         // K-range [lbase, lbase+48)

    __shared__ __align__(16) float p[Ll];
    float* pp = &p[lbase];

    const float* xbase = inputs + (size_t)b * Tt * Ll;

    // ---- E in explicit scalar v2f registers ----
    // Ev_i = (exp(trans[lbase+i][cA]), exp(trans[lbase+i][cB]))
    // Ep_k = (exp(trans[lbase+2k][cC]), exp(trans[lbase+2k+1][cC]))
#define DECLV(i) v2f Ev##i;
#define DECLP(k) v2f Ep##k;
    REP48(DECLV)
    REP24(DECLP)
#define INITV(i) { const float* tr = trans + (size_t)(lbase + (i)) * Ll; \
                   Ev##i = (v2f){__expf(tr[cA]), __expf(tr[cB])}; }
    REP48(INITV)
#define INITP(k) { const float* tr = trans + (size_t)(lbase + 2*(k)) * Ll; \
                   Ep##k = (v2f){__expf(tr[cC]), __expf(tr[Ll + cC])}; }
    REP24(INITP)

    // ---- point_score + trans_score (off critical path, once) ----
    float score;
    {
        float psum = 0.f;
        const int* lbl = labels_idx + b * Tt;
        for (int t = tid; t < Tt; t += 64) {
            int i0 = lbl[t];
            psum += xbase[t * Ll + i0];
            if (t < Tt - 1) psum += trans[i0 * Ll + lbl[t + 1]];
        }
        #pragma unroll
        for (int off = 32; off; off >>= 1) psum += __shfl_xor(psum, off, 64);
        score = psum;
    }

    // ---- init: P_0 = exp(state_0 - 0); dup halves write identical values ----
    p[cA] = __expf(xbase[cA]);
    p[cB] = __expf(xbase[cB]);
    p[cC] = __expf(xbase[cC]);

    // ---- x prefetch pipeline, depth 4, three columns ----
    float xA0 = xbase[1*Ll+cA], xB0 = xbase[1*Ll+cB], xC0 = xbase[1*Ll+cC];
    float xA1 = xbase[2*Ll+cA], xB1 = xbase[2*Ll+cB], xC1 = xbase[2*Ll+cC];
    float xA2 = xbase[3*Ll+cA], xB2 = xbase[3*Ll+cB], xC2 = xbase[3*Ll+cC];
    float xA3 = xbase[4*Ll+cA], xB3 = xbase[4*Ll+cB], xC3 = xbase[4*Ll+cC];

    float c = 0.f, uP = 0.f, uNext = 0.f;
    float tA = 0.f, tB = 0.f, tC = 0.f;

    for (int t = 1; t < Tt; ++t) {
        float xnA = 0.f, xnB = 0.f, xnC = 0.f;
        if (t + 4 < Tt) {
            const float* xr = xbase + (size_t)(t + 4) * Ll;
            xnA = xr[cA]; xnB = xr[cB]; xnC = xr[cC];
        }

        // ---- partial matvec over this lane's K-half ----
        v2f aV0 = {0.f,0.f}, aV1 = {0.f,0.f}, aV2 = {0.f,0.f}, aV3 = {0.f,0.f};
        v2f aS0 = {0.f,0.f}, aS1 = {0.f,0.f};
#define FMABLK(jj,i0,i1,i2,i3,k0,k1) { \
        v4f p4 = *reinterpret_cast<const v4f*>(pp + 4*(jj)); \
        aV0 += (v2f){p4.x,p4.x} * Ev##i0; \
        aV1 += (v2f){p4.y,p4.y} * Ev##i1; \
        aV2 += (v2f){p4.z,p4.z} * Ev##i2; \
        aV3 += (v2f){p4.w,p4.w} * Ev##i3; \
        aS0 += (v2f){p4.x,p4.y} * Ep##k0; \
        aS1 += (v2f){p4.z,p4.w} * Ep##k1; }
        FMABLK(0,  0, 1, 2, 3,  0, 1)
        FMABLK(1,  4, 5, 6, 7,  2, 3)
        FMABLK(2,  8, 9,10,11,  4, 5)
        FMABLK(3, 12,13,14,15,  6, 7)
        FMABLK(4, 16,17,18,19,  8, 9)
        FMABLK(5, 20,21,22,23, 10,11)
        FMABLK(6, 24,25,26,27, 12,13)
        FMABLK(7, 28,29,30,31, 14,15)
        FMABLK(8, 32,33,34,35, 16,17)
        FMABLK(9, 36,37,38,39, 18,19)
        FMABLK(10,40,41,42,43, 20,21)
        FMABLK(11,44,45,46,47, 22,23)

        v2f aV = (aV0 + aV1) + (aV2 + aV3);
        v2f aSp = aS0 + aS1;
        float aS = aSp.x + aSp.y;

        // cross-half combine (partner lane holds the other K-half)
        float totA = aV.x + __shfl_xor(aV.x, 32, 64);
        float totB = aV.y + __shfl_xor(aV.y, 32, 64);
        float totC = aS   + __shfl_xor(aS,   32, 64);

        c += uP;
        tA = __logf(totA) + xA0;          // state_t[cA] = tA + c
        tB = __logf(totB) + xB0;
        tC = __logf(totC) + xC0;
        float un = __shfl(tA, 0, 64);     // col 0 value — next step's stale shift
        float pA = __expf(tA - uNext);
        float pB = __expf(tB - uNext);
        float pC = __expf(tC - uNext);
        p[cA] = pA;                       // dup halves write identical values
        p[cB] = pB;
        p[cC] = pC;
        uP = uNext; uNext = un;

        xA0=xA1; xA1=xA2; xA2=xA3; xA3=xnA;
        xB0=xB1; xB1=xB2; xB2=xB3; xB3=xnB;
        xC0=xC1; xC1=xC2; xC2=xC3; xC3=xnC;
    }

    // ---- log_norm: lanes 0..31 hold all 96 cols (3 each); groups identical ----
    float M = fmaxf(fmaxf(tA, tB), tC);
    #pragma unroll
    for (int off = 16; off; off >>= 1) M = fmaxf(M, __shfl_xor(M, off, 64));
    float e = __expf(tA - M) + __expf(tB - M) + __expf(tC - M);
    #pragma unroll
    for (int off = 16; off; off >>= 1) e += __shfl_xor(e, off, 64);

    if (tid == 0) {
        out[b] = M + __logf(e) + c - score;
    }
}

extern "C" void kernel_launch(void* const* d_in, const int* in_sizes, int n_in,
                              void* d_out, int out_size, void* d_ws, size_t ws_size,
                              hipStream_t stream) {
    const float* inputs     = (const float*)d_in[0];
    const int*   labels_idx = (const int*)d_in[1];
    const float* trans      = (const float*)d_in[2];
    float*       out        = (float*)d_out;

    crf_fwd_kernel<<<dim3(Bb), dim3(64), 0, stream>>>(inputs, labels_idx, trans, out);
}

// Round 4
// 556.398 us; speedup vs baseline: 1.1998x; 1.1050x over previous
//
#include <hip/hip_runtime.h>
#include <math.h>

#define Bb 128
#define Tt 1024
#define Ll 96

typedef float v2f __attribute__((ext_vector_type(2)));
typedef float v4f __attribute__((ext_vector_type(4)));

// One block per batch, ONE wave, no barriers. Lane pair (m, m+32) with j=m&31
// owns columns {j, 32+j, 64+j}; half h=m>>5 covers K-range [48h,48h+48).
// E in explicit scalar v2f registers; amdgpu_waves_per_eu(1,1) pins the
// regalloc budget at 512 VGPRs (R1-R3 post-mortem: default ~128 budget spilled
// E to scratch — VGPR_Count 68/124/104 < |E|).
// Linear-space recurrence: no log/exp on the serial chain.
//   Praw_t[m] = (sum_l p[l] * E[l][m]) * X_t[m],  X_t = exp(x_t) (off-chain)
//   p_t[m]    = Praw_t[m] * inv,   inv = 1/Praw_{t-1}[col0]   (stale, off-chain)
//   c        += log(Praw_{t-1}[col0])                          (off-chain)
// Invariant: state_t[m] = log(p_t[m]) + c_t.  logZ = log(sum_m p[m]) + c.

#define REP48(M) M(0) M(1) M(2) M(3) M(4) M(5) M(6) M(7) M(8) M(9) M(10) M(11) \
  M(12) M(13) M(14) M(15) M(16) M(17) M(18) M(19) M(20) M(21) M(22) M(23) \
  M(24) M(25) M(26) M(27) M(28) M(29) M(30) M(31) M(32) M(33) M(34) M(35) \
  M(36) M(37) M(38) M(39) M(40) M(41) M(42) M(43) M(44) M(45) M(46) M(47)
#define REP24(M) M(0) M(1) M(2) M(3) M(4) M(5) M(6) M(7) M(8) M(9) M(10) M(11) \
  M(12) M(13) M(14) M(15) M(16) M(17) M(18) M(19) M(20) M(21) M(22) M(23)

__global__ __launch_bounds__(64) __attribute__((amdgpu_waves_per_eu(1, 1)))
void crf_fwd_kernel(
    const float* __restrict__ inputs,      // (B, T, L) fp32
    const int*   __restrict__ labels_idx,  // (B, T) int32
    const float* __restrict__ trans,       // (L, L) fp32
    float*       __restrict__ out)         // (B, 1) fp32
{
    const int b    = blockIdx.x;
    const int tid  = threadIdx.x;        // 0..63
    const int j    = tid & 31;
    const int half = tid >> 5;
    const int cA   = j;
    const int cB   = 32 + j;
    const int cC   = 64 + j;
    const int lbase = 48 * half;         // K-range [lbase, lbase+48)

    __shared__ __align__(16) float p[Ll];
    float* pp = &p[lbase];

    const float* xbase = inputs + (size_t)b * Tt * Ll;

    // ---- E in explicit scalar v2f registers ----
#define DECLV(i) v2f Ev##i;
#define DECLP(k) v2f Ep##k;
    REP48(DECLV)
    REP24(DECLP)
#define INITV(i) { const float* tr = trans + (size_t)(lbase + (i)) * Ll; \
                   Ev##i = (v2f){__expf(tr[cA]), __expf(tr[cB])}; }
    REP48(INITV)
#define INITP(k) { const float* tr = trans + (size_t)(lbase + 2*(k)) * Ll; \
                   Ep##k = (v2f){__expf(tr[cC]), __expf(tr[Ll + cC])}; }
    REP24(INITP)

    // ---- point_score + trans_score (off critical path, once) ----
    float score;
    {
        float psum = 0.f;
        const int* lbl = labels_idx + b * Tt;
        for (int t = tid; t < Tt; t += 64) {
            int i0 = lbl[t];
            psum += xbase[t * Ll + i0];
            if (t < Tt - 1) psum += trans[i0 * Ll + lbl[t + 1]];
        }
        #pragma unroll
        for (int off = 32; off; off >>= 1) psum += __shfl_xor(psum, off, 64);
        score = psum;
    }

    // ---- init: P_0 = exp(state_0); normalizer seed from col 0 ----
    float s0A = xbase[cA];
    p[cA] = __expf(s0A);
    p[cB] = __expf(xbase[cB]);
    p[cC] = __expf(xbase[cC]);
    float x00  = __shfl(s0A, 0, 64);   // state_0[col 0]
    float inv  = __expf(-x00);         // 1 / Praw_{t-1}[0]
    float lnrm = x00;                  // log(Praw_{t-1}[0])

    // ---- x prefetch pipeline, depth 4, three columns ----
    float xA0 = xbase[1*Ll+cA], xB0 = xbase[1*Ll+cB], xC0 = xbase[1*Ll+cC];
    float xA1 = xbase[2*Ll+cA], xB1 = xbase[2*Ll+cB], xC1 = xbase[2*Ll+cC];
    float xA2 = xbase[3*Ll+cA], xB2 = xbase[3*Ll+cB], xC2 = xbase[3*Ll+cC];
    float xA3 = xbase[4*Ll+cA], xB3 = xbase[4*Ll+cB], xC3 = xbase[4*Ll+cC];

    float c = 0.f;
    float pA = 0.f, pB = 0.f, pC = 0.f;

    for (int t = 1; t < Tt; ++t) {
        // prefetch x row t+4 (clamped; loads stay in flight — no barriers)
        int tp = t + 4; if (tp > Tt - 1) tp = Tt - 1;
        const float* xr = xbase + (size_t)tp * Ll;
        float xnA = xr[cA], xnB = xr[cB], xnC = xr[cC];

        // X = exp(x_t) — off the serial chain (x loaded 4 iters ago)
        float XA = __expf(xA0), XB = __expf(xB0), XC = __expf(xC0);

        // ---- partial matvec over this lane's K-half ----
        v2f aV0 = {0.f,0.f}, aV1 = {0.f,0.f}, aV2 = {0.f,0.f}, aV3 = {0.f,0.f};
        v2f aS0 = {0.f,0.f}, aS1 = {0.f,0.f};
#define FMABLK(jj,i0,i1,i2,i3,k0,k1) { \
        v4f p4 = *reinterpret_cast<const v4f*>(pp + 4*(jj)); \
        aV0 += (v2f){p4.x,p4.x} * Ev##i0; \
        aV1 += (v2f){p4.y,p4.y} * Ev##i1; \
        aV2 += (v2f){p4.z,p4.z} * Ev##i2; \
        aV3 += (v2f){p4.w,p4.w} * Ev##i3; \
        aS0 += (v2f){p4.x,p4.y} * Ep##k0; \
        aS1 += (v2f){p4.z,p4.w} * Ep##k1; }
        FMABLK(0,  0, 1, 2, 3,  0, 1)
        FMABLK(1,  4, 5, 6, 7,  2, 3)
        FMABLK(2,  8, 9,10,11,  4, 5)
        FMABLK(3, 12,13,14,15,  6, 7)
        FMABLK(4, 16,17,18,19,  8, 9)
        FMABLK(5, 20,21,22,23, 10,11)
        FMABLK(6, 24,25,26,27, 12,13)
        FMABLK(7, 28,29,30,31, 14,15)
        FMABLK(8, 32,33,34,35, 16,17)
        FMABLK(9, 36,37,38,39, 18,19)
        FMABLK(10,40,41,42,43, 20,21)
        FMABLK(11,44,45,46,47, 22,23)

        v2f aV = (aV0 + aV1) + (aV2 + aV3);
        v2f aSp = aS0 + aS1;
        float aS = aSp.x + aSp.y;

        // cross-half combine (partner lane holds the other K-half)
        float totA = aV.x + __shfl_xor(aV.x, 32, 64);
        float totB = aV.y + __shfl_xor(aV.y, 32, 64);
        float totC = aS   + __shfl_xor(aS,   32, 64);

        float PrA = totA * XA;
        float PrB = totB * XB;
        float PrC = totC * XC;
        pA = PrA * inv;                 // stale normalizer — no log/exp on chain
        pB = PrB * inv;
        pC = PrC * inv;
        p[cA] = pA;                     // dup halves write identical values
        p[cB] = pB;
        p[cC] = pC;

        c += lnrm;                      // C_t = C_{t-1} + log(Praw_{t-1}[0])
        float nrm = __shfl(PrA, 0, 64); // Praw_t[col 0] — for next iteration
        inv  = 1.0f / nrm;              // off-chain: full iteration of slack
        lnrm = __logf(nrm);

        xA0=xA1; xA1=xA2; xA2=xA3; xA3=xnA;
        xB0=xB1; xB1=xB2; xB2=xB3; xB3=xnB;
        xC0=xC1; xC1=xC2; xC2=xC3; xC3=xnC;
    }

    // ---- logZ = log(sum_m p[m]) + c  (halves hold identical full values) ----
    float e = pA + pB + pC;
    #pragma unroll
    for (int off = 16; off; off >>= 1) e += __shfl_xor(e, off, 64);

    if (tid == 0) {
        out[b] = __logf(e) + c - score;
    }
}

extern "C" void kernel_launch(void* const* d_in, const int* in_sizes, int n_in,
                              void* d_out, int out_size, void* d_ws, size_t ws_size,
                              hipStream_t stream) {
    const float* inputs     = (const float*)d_in[0];
    const int*   labels_idx = (const int*)d_in[1];
    const float* trans      = (const float*)d_in[2];
    float*       out        = (float*)d_out;

    crf_fwd_kernel<<<dim3(Bb), dim3(64), 0, stream>>>(inputs, labels_idx, trans, out);
}